// Round 15
// baseline (59.867 us; speedup 1.0000x reference)
//
#include <hip/hip_runtime.h>
#include <stdint.h>

// ---------------------------------------------------------------------------
// AdditiveAttention (Bahdanau) + gumbel-softmax(tau=0.01), channel 0.
//
// R15 = VISIBILITY ROUND. proj + attn are BYTE-IDENTICAL to R14 (passing,
// 44.0us). Only change: attn gridDim.z = 8 (was 4); blocks with z>>2==1
// redo identical work and write identical values (benign duplicate store,
// deterministic). attn dispatch ~2x (~60us) -> surfaces above the ~40us
// harness fillBuffer dispatches in rocprof top-5, giving us VGPR_Count /
// VALUBusy / Occupancy / LDS_BANK_CONFLICT for the hot kernel for the
// first time since R9. dur_us cost this round is accepted.
// Pre-committed branches: VGPR>=200 -> pressure fix; VALUBusy>=85 ->
// wave-compaction of gumbel; VALUBusy<=60 -> 4-way interleaved threefry.
// ---------------------------------------------------------------------------

#define BB 4
#define LLEN 512
#define DD 256
#define HH 128

#define TWO_LOG2E 2.8853900817779268f   // 2*log2(e)
#define LOG2E_100 144.26950408889634f   // 100*log2(e)

__device__ __forceinline__ uint32_t rotl32(uint32_t v, int r) {
  return __builtin_amdgcn_alignbit(v, v, 32 - r);
}

// Threefry-2x32, key = (0, 42)
__device__ __forceinline__ void tf2x32(uint32_t x0, uint32_t x1,
                                       uint32_t& o0, uint32_t& o1) {
  const uint32_t k0 = 0u;
  const uint32_t k1 = 42u;
  const uint32_t k2 = 0x1BD11BDAu ^ k0 ^ k1;

  x0 += k0; x1 += k1;
#define TFR(r) { x0 += x1; x1 = rotl32(x1, (r)); x1 ^= x0; }
  TFR(13) TFR(15) TFR(26) TFR(6)
  x0 += k1; x1 += k2 + 1u;
  TFR(17) TFR(29) TFR(16) TFR(24)
  x0 += k2; x1 += k0 + 2u;
  TFR(13) TFR(15) TFR(26) TFR(6)
  x0 += k0; x1 += k1 + 3u;
  TFR(17) TFR(29) TFR(16) TFR(24)
  x0 += k1; x1 += k2 + 4u;
  TFR(13) TFR(15) TFR(26) TFR(6)
  x0 += k2; x1 += k0 + 5u;
#undef TFR
  o0 = x0; o1 = x1;
}

// u in (0,1) from jax partitionable random_bits (counter (0,flat), o0^o1)
__device__ __forceinline__ float jax_u01(uint32_t flat) {
  uint32_t o0, o1;
  tf2x32(0u, flat, o0, o1);
  const uint32_t bits = o0 ^ o1;
  const float f = __uint_as_float((bits >> 9) | 0x3F800000u) - 1.0f;
  return fmaxf(f, 1.17549435e-38f);
}

// ---------------------------------------------------------------------------
// Kernel A: projections -> EQ = exp2(c * q.Wq^T), EK = exp2(c * k.Wk^T).
// (R8-R14 verbatim)
// ---------------------------------------------------------------------------
__global__ __launch_bounds__(128) void proj_kernel(
    const float* __restrict__ queries, const float* __restrict__ keys,
    const float* __restrict__ Wq, const float* __restrict__ Wk,
    float* __restrict__ EQ, float* __restrict__ EK) {
  const int blk = blockIdx.x;
  const bool isK = blk >= 512;
  const int rb = (isK ? blk - 512 : blk) * 4;
  const float* __restrict__ in = isK ? keys : queries;
  const float* __restrict__ W  = isK ? Wk : Wq;
  float* __restrict__ outp     = isK ? EK : EQ;

  __shared__ float rows[4][DD];
  const float4* in4 = reinterpret_cast<const float4*>(in + (size_t)rb * DD);
  float4* rows4 = reinterpret_cast<float4*>(&rows[0][0]);
  #pragma unroll
  for (int t = threadIdx.x; t < 4 * DD / 4; t += 128) rows4[t] = in4[t];
  __syncthreads();

  const int h = threadIdx.x;
  const float4* W4 = reinterpret_cast<const float4*>(W + (size_t)h * DD);
  float a0 = 0.f, a1 = 0.f, a2 = 0.f, a3 = 0.f;
  #pragma unroll 8
  for (int d4 = 0; d4 < DD / 4; ++d4) {
    const float4 w = W4[d4];
    const int d = d4 * 4;
    a0 = fmaf(w.x, rows[0][d], fmaf(w.y, rows[0][d+1], fmaf(w.z, rows[0][d+2], fmaf(w.w, rows[0][d+3], a0))));
    a1 = fmaf(w.x, rows[1][d], fmaf(w.y, rows[1][d+1], fmaf(w.z, rows[1][d+2], fmaf(w.w, rows[1][d+3], a1))));
    a2 = fmaf(w.x, rows[2][d], fmaf(w.y, rows[2][d+1], fmaf(w.z, rows[2][d+2], fmaf(w.w, rows[2][d+3], a2))));
    a3 = fmaf(w.x, rows[3][d], fmaf(w.y, rows[3][d+1], fmaf(w.z, rows[3][d+2], fmaf(w.w, rows[3][d+3], a3))));
  }
  float* orow = outp + (size_t)rb * HH + h;
  orow[0 * HH] = __builtin_amdgcn_exp2f(a0 * TWO_LOG2E);
  orow[1 * HH] = __builtin_amdgcn_exp2f(a1 * TWO_LOG2E);
  orow[2 * HH] = __builtin_amdgcn_exp2f(a2 * TWO_LOG2E);
  orow[3 * HH] = __builtin_amdgcn_exp2f(a3 * TWO_LOG2E);
}

// ---------------------------------------------------------------------------
// Shared-rcp 4-group site macro (identical to R9-R14, passing)
// ---------------------------------------------------------------------------
#define GRP(accv, qv, kv, wd) {                                       \
    float4 A_;                                                        \
    A_.x = fmaf((qv).x, (kv).x, 1.0f);                                \
    A_.y = fmaf((qv).y, (kv).y, 1.0f);                                \
    A_.z = fmaf((qv).z, (kv).z, 1.0f);                                \
    A_.w = fmaf((qv).w, (kv).w, 1.0f);                                \
    const float p01_ = A_.x * A_.y;                                   \
    const float p23_ = A_.z * A_.w;                                   \
    const float n01_ = fmaf((wd).x, A_.y, (wd).y * A_.x);             \
    const float n23_ = fmaf((wd).z, A_.w, (wd).w * A_.z);             \
    const float num_ = fmaf(n01_, p23_, n23_ * p01_);                 \
    const float rc_  = __builtin_amdgcn_rcpf(p01_ * p23_);            \
    (accv) = fmaf(num_, rc_, (accv)); }

// ---------------------------------------------------------------------------
// attn_kernel: 32i x 64j tile, 256 thr, 8 outputs/thread, fused gumbel
// epilogue — BYTE-IDENTICAL body to R14. gridDim.z=8: b = z&3, duplicate
// half writes identical values (visibility doubling).
// ---------------------------------------------------------------------------
__global__ __launch_bounds__(256) void attn_kernel(
    const float* __restrict__ EQ, const float* __restrict__ EK,
    const int* __restrict__ mask, const float* __restrict__ Wv,
    float* __restrict__ out) {
  __shared__ float4 QL[32][33];
  __shared__ float4 KL[64][33];
  __shared__ float4 wdL[32];

  const int bi = blockIdx.x, bj = blockIdx.y, b = blockIdx.z & (BB - 1);
  const int i0 = bi * 32, j0 = bj * 64;

  const float4* Q4 = reinterpret_cast<const float4*>(EQ) + ((size_t)b * LLEN + i0) * (HH / 4);
  const float4* K4 = reinterpret_cast<const float4*>(EK) + ((size_t)b * LLEN + j0) * (HH / 4);
  for (int t = threadIdx.x; t < 1024 + 2048; t += 256) {
    if (t < 1024) {
      QL[t >> 5][t & 31] = Q4[t];
    } else {
      const int u = t - 1024;
      KL[u >> 5][u & 31] = K4[u];
    }
  }
  if (threadIdx.x < 32) {
    const float4 w0 = reinterpret_cast<const float4*>(Wv)[threadIdx.x];
    const float4 w1 = reinterpret_cast<const float4*>(Wv)[32 + threadIdx.x];
    float4 wd; wd.x = w0.x - w1.x; wd.y = w0.y - w1.y;
    wd.z = w0.z - w1.z; wd.w = w0.w - w1.w;
    wdL[threadIdx.x] = wd;
  }
  __syncthreads();

  const int jj = threadIdx.x & 31;   // cols j0+jj, j0+jj+32
  const int ib = threadIdx.x >> 5;   // rows ib, ib+8, ib+16, ib+24

  const uint32_t row0 = (uint32_t)b * LLEN + i0 + ib;
  const uint32_t col0 = j0 + jj;
  int mreg[4][2];
  #pragma unroll
  for (int r = 0; r < 4; ++r)
    #pragma unroll
    for (int c = 0; c < 2; ++c)
      mreg[r][c] = mask[(row0 + 8u * r) * LLEN + col0 + 32u * c];

  float Swd = 0.f;
  #pragma unroll
  for (int t = 0; t < 32; ++t) {
    const float4 wd = wdL[t];
    Swd += (wd.x + wd.y) + (wd.z + wd.w);
  }

  float acc[4][2] = {{0.f,0.f},{0.f,0.f},{0.f,0.f},{0.f,0.f}};

  #pragma unroll 4
  for (int h4 = 0; h4 < HH / 4; ++h4) {
    const float4 kv0 = KL[jj][h4];
    const float4 kv1 = KL[jj + 32][h4];
    const float4 wd  = wdL[h4];
    const float4 qv0 = QL[ib][h4];
    const float4 qv1 = QL[ib + 8][h4];
    const float4 qv2 = QL[ib + 16][h4];
    const float4 qv3 = QL[ib + 24][h4];
    GRP(acc[0][0], qv0, kv0, wd) GRP(acc[0][1], qv0, kv1, wd)
    GRP(acc[1][0], qv1, kv0, wd) GRP(acc[1][1], qv1, kv1, wd)
    GRP(acc[2][0], qv2, kv0, wd) GRP(acc[2][1], qv2, kv1, wd)
    GRP(acc[3][0], qv3, kv0, wd) GRP(acc[3][1], qv3, kv1, wd)
  }

  // fused branchless epilogue: dense gumbel, coalesced writes
  #pragma unroll
  for (int r = 0; r < 4; ++r) {
    #pragma unroll
    for (int c = 0; c < 2; ++c) {
      const uint32_t idx = (row0 + 8u * r) * LLEN + col0 + 32u * c;
      const float l0 = __log2f(jax_u01(idx * 2u));
      const float l1 = __log2f(jax_u01(idx * 2u + 1u));
      const float rl = l1 * __builtin_amdgcn_rcpf(l0);
      const float g_ = 100.0f * __log2f(rl);
      const float d_ = fmaf(-2.0f, acc[r][c], Swd);
      const float t_ = fmaf(d_, LOG2E_100, g_);
      const float o_ = __builtin_amdgcn_rcpf(1.0f + __builtin_amdgcn_exp2f(-t_));
      out[idx] = (mreg[r][c] >= 2) ? o_ : 1.0f;
    }
  }
}

extern "C" void kernel_launch(void* const* d_in, const int* in_sizes, int n_in,
                              void* d_out, int out_size, void* d_ws, size_t ws_size,
                              hipStream_t stream) {
  const float* queries = (const float*)d_in[0];
  const float* keys    = (const float*)d_in[1];
  const int*   mask    = (const int*)d_in[2];
  const float* Wq      = (const float*)d_in[3];
  const float* Wk      = (const float*)d_in[4];
  const float* Wv      = (const float*)d_in[5];
  float* out = (float*)d_out;

  float* EQ = (float*)d_ws;                 // 1 MB
  float* EK = EQ + (size_t)BB * LLEN * HH;  // 1 MB

  proj_kernel<<<dim3(1024), dim3(128), 0, stream>>>(
      queries, keys, Wq, Wk, EQ, EK);
  // gridDim.z = 2*BB: duplicate half (z>>2==1) writes identical values —
  // doubles attn dispatch duration so rocprof top-5 shows its counters.
  attn_kernel<<<dim3(LLEN / 32, LLEN / 64, 2 * BB), dim3(256), 0, stream>>>(
      EQ, EK, mask, Wv, out);
}

// Round 16
// 43.849 us; speedup vs baseline: 1.3653x; 1.3653x over previous
//
#include <hip/hip_runtime.h>
#include <stdint.h>

// ---------------------------------------------------------------------------
// AdditiveAttention (Bahdanau) + gumbel-softmax(tau=0.01), channel 0.
//
// out[b,i,j] = (mask==1) ? 1.0 : sigmoid((d + g0 - g1)*100),
//   d = sum_h tanh(q+k)*(w0-w1);  g bit-exact jax threefry (verified R3-R15).
//
// R16: ILP fix for the threefry epilogue. R15 counters (VALUBusy 53%,
// VGPR 120, occ 18.5%, conflicts 0) => latency-bound: threefry is a ~90-op
// SERIAL dep chain and the compiler schedules the 16 chains sequentially;
// at ~3 waves/SIMD nothing fills the dep-latency gaps. Fix: tf2x32_x4 —
// 4 independent chains interleaved round-by-round (static-index arrays,
// fully unrolled). Epilogue in two halves of 4 sites (8 chains each) to
// bound VGPR. ILP 4 >= dep-latency/issue-rate -> VALU slots fill at 3
// waves/SIMD. Loop/proj/math bit-identical to R14; grid back to z=4.
// ---------------------------------------------------------------------------

#define BB 4
#define LLEN 512
#define DD 256
#define HH 128

#define TWO_LOG2E 2.8853900817779268f   // 2*log2(e)
#define LOG2E_100 144.26950408889634f   // 100*log2(e)

__device__ __forceinline__ uint32_t rotl32(uint32_t v, int r) {
  return __builtin_amdgcn_alignbit(v, v, 32 - r);
}

// ---- 4 independent threefry-2x32 chains, interleaved round-by-round ----
__device__ __forceinline__ void tf4_round(uint32_t x0[4], uint32_t x1[4],
                                          const int r) {
  #pragma unroll
  for (int i = 0; i < 4; ++i) {
    x0[i] += x1[i];
    x1[i] = rotl32(x1[i], r);
    x1[i] ^= x0[i];
  }
}
__device__ __forceinline__ void tf4_key(uint32_t x0[4], uint32_t x1[4],
                                        const uint32_t a, const uint32_t b) {
  #pragma unroll
  for (int i = 0; i < 4; ++i) { x0[i] += a; x1[i] += b; }
}

// counter (0, c[i]), key (0,42); returns o0^o1 per chain
__device__ __forceinline__ void tf2x32_x4(const uint32_t c[4], uint32_t o[4]) {
  const uint32_t k0 = 0u;
  const uint32_t k1 = 42u;
  const uint32_t k2 = 0x1BD11BDAu ^ k0 ^ k1;   // 0x1BD11BF0

  uint32_t x0[4], x1[4];
  #pragma unroll
  for (int i = 0; i < 4; ++i) { x0[i] = k0; x1[i] = c[i] + k1; }

  tf4_round(x0, x1, 13); tf4_round(x0, x1, 15);
  tf4_round(x0, x1, 26); tf4_round(x0, x1, 6);
  tf4_key(x0, x1, k1, k2 + 1u);
  tf4_round(x0, x1, 17); tf4_round(x0, x1, 29);
  tf4_round(x0, x1, 16); tf4_round(x0, x1, 24);
  tf4_key(x0, x1, k2, k0 + 2u);
  tf4_round(x0, x1, 13); tf4_round(x0, x1, 15);
  tf4_round(x0, x1, 26); tf4_round(x0, x1, 6);
  tf4_key(x0, x1, k0, k1 + 3u);
  tf4_round(x0, x1, 17); tf4_round(x0, x1, 29);
  tf4_round(x0, x1, 16); tf4_round(x0, x1, 24);
  tf4_key(x0, x1, k1, k2 + 4u);
  tf4_round(x0, x1, 13); tf4_round(x0, x1, 15);
  tf4_round(x0, x1, 26); tf4_round(x0, x1, 6);
  tf4_key(x0, x1, k2, k0 + 5u);

  #pragma unroll
  for (int i = 0; i < 4; ++i) o[i] = x0[i] ^ x1[i];
}

__device__ __forceinline__ float u01_from_bits(uint32_t bits) {
  const float f = __uint_as_float((bits >> 9) | 0x3F800000u) - 1.0f;
  return fmaxf(f, 1.17549435e-38f);
}

// ---------------------------------------------------------------------------
// Kernel A: projections -> EQ = exp2(c * q.Wq^T), EK = exp2(c * k.Wk^T).
// (R8-R15 verbatim)
// ---------------------------------------------------------------------------
__global__ __launch_bounds__(128) void proj_kernel(
    const float* __restrict__ queries, const float* __restrict__ keys,
    const float* __restrict__ Wq, const float* __restrict__ Wk,
    float* __restrict__ EQ, float* __restrict__ EK) {
  const int blk = blockIdx.x;
  const bool isK = blk >= 512;
  const int rb = (isK ? blk - 512 : blk) * 4;
  const float* __restrict__ in = isK ? keys : queries;
  const float* __restrict__ W  = isK ? Wk : Wq;
  float* __restrict__ outp     = isK ? EK : EQ;

  __shared__ float rows[4][DD];
  const float4* in4 = reinterpret_cast<const float4*>(in + (size_t)rb * DD);
  float4* rows4 = reinterpret_cast<float4*>(&rows[0][0]);
  #pragma unroll
  for (int t = threadIdx.x; t < 4 * DD / 4; t += 128) rows4[t] = in4[t];
  __syncthreads();

  const int h = threadIdx.x;
  const float4* W4 = reinterpret_cast<const float4*>(W + (size_t)h * DD);
  float a0 = 0.f, a1 = 0.f, a2 = 0.f, a3 = 0.f;
  #pragma unroll 8
  for (int d4 = 0; d4 < DD / 4; ++d4) {
    const float4 w = W4[d4];
    const int d = d4 * 4;
    a0 = fmaf(w.x, rows[0][d], fmaf(w.y, rows[0][d+1], fmaf(w.z, rows[0][d+2], fmaf(w.w, rows[0][d+3], a0))));
    a1 = fmaf(w.x, rows[1][d], fmaf(w.y, rows[1][d+1], fmaf(w.z, rows[1][d+2], fmaf(w.w, rows[1][d+3], a1))));
    a2 = fmaf(w.x, rows[2][d], fmaf(w.y, rows[2][d+1], fmaf(w.z, rows[2][d+2], fmaf(w.w, rows[2][d+3], a2))));
    a3 = fmaf(w.x, rows[3][d], fmaf(w.y, rows[3][d+1], fmaf(w.z, rows[3][d+2], fmaf(w.w, rows[3][d+3], a3))));
  }
  float* orow = outp + (size_t)rb * HH + h;
  orow[0 * HH] = __builtin_amdgcn_exp2f(a0 * TWO_LOG2E);
  orow[1 * HH] = __builtin_amdgcn_exp2f(a1 * TWO_LOG2E);
  orow[2 * HH] = __builtin_amdgcn_exp2f(a2 * TWO_LOG2E);
  orow[3 * HH] = __builtin_amdgcn_exp2f(a3 * TWO_LOG2E);
}

// ---------------------------------------------------------------------------
// Shared-rcp 4-group site macro (identical to R9-R15, passing)
// ---------------------------------------------------------------------------
#define GRP(accv, qv, kv, wd) {                                       \
    float4 A_;                                                        \
    A_.x = fmaf((qv).x, (kv).x, 1.0f);                                \
    A_.y = fmaf((qv).y, (kv).y, 1.0f);                                \
    A_.z = fmaf((qv).z, (kv).z, 1.0f);                                \
    A_.w = fmaf((qv).w, (kv).w, 1.0f);                                \
    const float p01_ = A_.x * A_.y;                                   \
    const float p23_ = A_.z * A_.w;                                   \
    const float n01_ = fmaf((wd).x, A_.y, (wd).y * A_.x);             \
    const float n23_ = fmaf((wd).z, A_.w, (wd).w * A_.z);             \
    const float num_ = fmaf(n01_, p23_, n23_ * p01_);                 \
    const float rc_  = __builtin_amdgcn_rcpf(p01_ * p23_);            \
    (accv) = fmaf(num_, rc_, (accv)); }

// ---------------------------------------------------------------------------
// attn_kernel: 32i x 64j tile (grid 16x8x4), 256 thr, 8 outputs/thread.
// Fused epilogue with explicit 4-way-interleaved threefry (two halves).
// ---------------------------------------------------------------------------
__global__ __launch_bounds__(256) void attn_kernel(
    const float* __restrict__ EQ, const float* __restrict__ EK,
    const int* __restrict__ mask, const float* __restrict__ Wv,
    float* __restrict__ out) {
  __shared__ float4 QL[32][33];
  __shared__ float4 KL[64][33];
  __shared__ float4 wdL[32];

  const int bi = blockIdx.x, bj = blockIdx.y, b = blockIdx.z;
  const int i0 = bi * 32, j0 = bj * 64;

  const float4* Q4 = reinterpret_cast<const float4*>(EQ) + ((size_t)b * LLEN + i0) * (HH / 4);
  const float4* K4 = reinterpret_cast<const float4*>(EK) + ((size_t)b * LLEN + j0) * (HH / 4);
  for (int t = threadIdx.x; t < 1024 + 2048; t += 256) {
    if (t < 1024) {
      QL[t >> 5][t & 31] = Q4[t];
    } else {
      const int u = t - 1024;
      KL[u >> 5][u & 31] = K4[u];
    }
  }
  if (threadIdx.x < 32) {
    const float4 w0 = reinterpret_cast<const float4*>(Wv)[threadIdx.x];
    const float4 w1 = reinterpret_cast<const float4*>(Wv)[32 + threadIdx.x];
    float4 wd; wd.x = w0.x - w1.x; wd.y = w0.y - w1.y;
    wd.z = w0.z - w1.z; wd.w = w0.w - w1.w;
    wdL[threadIdx.x] = wd;
  }
  __syncthreads();

  const int jj = threadIdx.x & 31;   // cols j0+jj, j0+jj+32
  const int ib = threadIdx.x >> 5;   // rows ib, ib+8, ib+16, ib+24

  const uint32_t row0 = (uint32_t)b * LLEN + i0 + ib;
  const uint32_t col0 = j0 + jj;
  int mreg[4][2];
  #pragma unroll
  for (int r = 0; r < 4; ++r)
    #pragma unroll
    for (int c = 0; c < 2; ++c)
      mreg[r][c] = mask[(row0 + 8u * r) * LLEN + col0 + 32u * c];

  float Swd = 0.f;
  #pragma unroll
  for (int t = 0; t < 32; ++t) {
    const float4 wd = wdL[t];
    Swd += (wd.x + wd.y) + (wd.z + wd.w);
  }

  float acc[4][2] = {{0.f,0.f},{0.f,0.f},{0.f,0.f},{0.f,0.f}};

  #pragma unroll 4
  for (int h4 = 0; h4 < HH / 4; ++h4) {
    const float4 kv0 = KL[jj][h4];
    const float4 kv1 = KL[jj + 32][h4];
    const float4 wd  = wdL[h4];
    const float4 qv0 = QL[ib][h4];
    const float4 qv1 = QL[ib + 8][h4];
    const float4 qv2 = QL[ib + 16][h4];
    const float4 qv3 = QL[ib + 24][h4];
    GRP(acc[0][0], qv0, kv0, wd) GRP(acc[0][1], qv0, kv1, wd)
    GRP(acc[1][0], qv1, kv0, wd) GRP(acc[1][1], qv1, kv1, wd)
    GRP(acc[2][0], qv2, kv0, wd) GRP(acc[2][1], qv2, kv1, wd)
    GRP(acc[3][0], qv3, kv0, wd) GRP(acc[3][1], qv3, kv1, wd)
  }

  // fused epilogue: two halves of 4 sites; 8 interleaved threefry chains
  // per half (2x tf2x32_x4). Math bit-identical to R13-R15.
  #pragma unroll
  for (int half = 0; half < 2; ++half) {
    uint32_t idx[4];
    float    dv[4];
    int      mm[4];
    #pragma unroll
    for (int k = 0; k < 4; ++k) {
      const int r = half * 2 + (k >> 1);
      const int c = k & 1;
      idx[k] = (row0 + 8u * r) * LLEN + col0 + 32u * c;
      dv[k]  = fmaf(-2.0f, acc[r][c], Swd);
      mm[k]  = mreg[r][c];
    }

    uint32_t c0[4], c1[4];
    #pragma unroll
    for (int k = 0; k < 4; ++k) { c0[k] = idx[k] * 2u; c1[k] = idx[k] * 2u + 1u; }
    uint32_t b0[4], b1[4];
    tf2x32_x4(c0, b0);
    tf2x32_x4(c1, b1);

    #pragma unroll
    for (int k = 0; k < 4; ++k) {
      const float l0 = __log2f(u01_from_bits(b0[k]));
      const float l1 = __log2f(u01_from_bits(b1[k]));
      const float rl = l1 * __builtin_amdgcn_rcpf(l0);
      const float g_ = 100.0f * __log2f(rl);
      const float t_ = fmaf(dv[k], LOG2E_100, g_);
      const float o_ = __builtin_amdgcn_rcpf(1.0f + __builtin_amdgcn_exp2f(-t_));
      out[idx[k]] = (mm[k] >= 2) ? o_ : 1.0f;
    }
  }
}

extern "C" void kernel_launch(void* const* d_in, const int* in_sizes, int n_in,
                              void* d_out, int out_size, void* d_ws, size_t ws_size,
                              hipStream_t stream) {
  const float* queries = (const float*)d_in[0];
  const float* keys    = (const float*)d_in[1];
  const int*   mask    = (const int*)d_in[2];
  const float* Wq      = (const float*)d_in[3];
  const float* Wk      = (const float*)d_in[4];
  const float* Wv      = (const float*)d_in[5];
  float* out = (float*)d_out;

  float* EQ = (float*)d_ws;                 // 1 MB
  float* EK = EQ + (size_t)BB * LLEN * HH;  // 1 MB

  proj_kernel<<<dim3(1024), dim3(128), 0, stream>>>(
      queries, keys, Wq, Wk, EQ, EK);
  attn_kernel<<<dim3(LLEN / 32, LLEN / 64, BB), dim3(256), 0, stream>>>(
      EQ, EK, mask, Wv, out);
}